// Round 2
// baseline (429.137 us; speedup 1.0000x reference)
//
#include <hip/hip_runtime.h>

typedef unsigned long long u64;
typedef unsigned int u32;
typedef unsigned short u16;

#define MAXD 5
#define BSH  6
#define BN   64        // nodes per bucket
#define NTH  256
#define CAPG 2816      // bucket-major record capacity (mean 2046, +17 sigma)
#define MAXC 1024      // compile-time bound on chunk count (NB <= MAXC)
#define HEMPTY 0xFFFFFFFFu

// ---------------------------------------------------------------------------
// R13: single persistent kernel with a SOFTWARE grid barrier (R12's
// hipLaunchCooperativeKernel was rejected at launch -> all-zero output).
// Co-residency: launch_bounds(256,4) -> >=4 blocks/CU (VGPR<=128; LDS
// 19.5KB -> 8/CU) -> capacity 1024 >= grid NB=782. Barrier = ockl pattern:
// syncthreads; t0: threadfence(release/wbL2) -> atomicAdd arrive ->
// relaxed agent-scope spin -> threadfence(acquire/invL2); syncthreads.
// Counter zeroed by a 4-byte memset each launch (graph-replay safe).
//
// Phases: 0 zero NFg | 1 chunk sort + depth-1 (edges in regs) |
// 2 merge->LDS + depth2 | 3 depth3 | 4 depth4 + matmul. Bucket records
// live in LDS across depths; V/CNT bucket-local in LDS.
//
// ws: NFg[N] F2[N] F3[N] (u64) | srcPack[64] nvalid bar (u32) |
//     recs[NB*CAPC] (u32) | segtab[NB*(NB+1)] (u16)
// ---------------------------------------------------------------------------

__device__ __forceinline__ void gbar(u32* bar, u32 target) {
    __syncthreads();
    if (threadIdx.x == 0) {
        __threadfence();                 // device-scope release (L2 writeback)
        atomicAdd(bar, 1u);
        while (__hip_atomic_load(bar, __ATOMIC_RELAXED,
                                 __HIP_MEMORY_SCOPE_AGENT) < target)
            __builtin_amdgcn_s_sleep(2);
        __threadfence();                 // device-scope acquire (L2 inv)
    }
    __syncthreads();
}

__global__ __launch_bounds__(NTH, 4) void fused(
    const int* __restrict__ h, const int* __restrict__ t, int E, int CE, int CAPC,
    int NB, u32* __restrict__ recs, u16* __restrict__ segtab,
    const int* __restrict__ anchor, int A,
    u64* __restrict__ NFg, u32* __restrict__ srcPack, int* __restrict__ nvalid,
    u32* __restrict__ bar,
    u64* __restrict__ F2g, u64* __restrict__ F3g,
    const float* __restrict__ embed, float* __restrict__ out, int N) {
    extern __shared__ u32 sh[];
    const int tid = threadIdx.x;
    const int b = blockIdx.x;
    const int lane = tid & 63, w = tid >> 6;
    const u32 nb = (u32)gridDim.x;

    // persistent LDS carve (valid phase 2 onward)
    u32* buf2 = sh;                      // [CAPG]            11264 B
    u64* NF   = (u64*)(sh + CAPG);       // [BN]              +512
    u64* Vl   = NF + BN;                 // [BN]              +512
    u64* CNTl = Vl + BN;                 // [BN]              +512 = 12800
    u32* scr  = (u32*)(CNTl + BN);       // phase-2 scratch
    u16* s0a  = (u16*)scr;               // [MAXC]            2048 B
    u32* loff = scr + MAXC / 2;          // [MAXC+1]
    u32* wS2  = loff + MAXC + 1;         // [4]
    u32* srcL = wS2 + 4;                 // [64]  (total 19220 B)

    // ---- phase 0: zero NFg ----
    { int i = b * NTH + tid; if (i < N) NFg[i] = 0ull; }
    gbar(bar, nb);

    // ---- phase 1: chunk sort + depth-1 ----
    {
        u32* cbuf  = sh;                 // [CAPC]
        u32* offs  = cbuf + CAPC;        // [NB]
        u32* cur   = offs + NB;          // [NB]
        u32* hsKey = cur + NB;           // [128]
        u32* hsBit = hsKey + 128;        // [128]
        u32* wS    = hsBit + 128;        // [4]
        int lo = b * CE, hi = min(E, lo + CE);
        int ne = hi - lo, nrec = 2 * ne;

        for (int i = tid; i < NB; i += NTH) cur[i] = 0u;
        if (tid < 128) hsKey[tid] = HEMPTY;
        __syncthreads();

        if (tid < 64) {  // wave 0: anchor gather + shfl dedup + hash insert
            int K = 2 * A;
            int a_ = (tid < K) ? anchor[(tid < A) ? tid : (tid - A)] : 0;
            int my = (tid < K) ? ((tid < A) ? h[a_] : t[a_]) : -1;
            bool uniq = (tid < K);
            for (int j = 0; j < 64; ++j) {
                int o = __shfl(my, j, 64);
                if (j < tid && o == my) uniq = false;
            }
            u64 mask = __ballot(uniq);
            if (b == 0 && tid == 0) *nvalid = (int)__popcll(mask);
            if (uniq) {
                u32 slot = ((u32)my * 2654435761u) >> 25;
                while (atomicCAS(&hsKey[slot], HEMPTY, (u32)my) != HEMPTY)
                    slot = (slot + 1) & 127u;
                hsBit[slot] = (u32)tid;
            }
            if (b == 0)
                srcPack[tid] = uniq ? (((u32)my << BSH) | (u32)tid) : HEMPTY;
        }

        // pass 1: hist; edges kept in regs for pass 2 (CE <= 4*NTH)
        u32 eu[4], ev[4];
#pragma unroll
        for (int k = 0; k < 4; ++k) {
            int i = tid + k * NTH;
            u32 uu = 0u, vv = 0u;
            if (i < ne) {
                uu = (u32)h[lo + i]; vv = (u32)t[lo + i];
                atomicAdd(&cur[vv >> BSH], 1u);
                atomicAdd(&cur[uu >> BSH], 1u);
            }
            eu[k] = uu; ev[k] = vv;
        }
        for (int i = tid + 4 * NTH; i < ne; i += NTH) {  // safety tail
            u32 uu = (u32)h[lo + i], vv = (u32)t[lo + i];
            atomicAdd(&cur[vv >> BSH], 1u);
            atomicAdd(&cur[uu >> BSH], 1u);
        }
        __syncthreads();

        // hierarchical exclusive scan: 4 contiguous entries/thread
        {
            u32 i0 = (u32)tid * 4;
            u32 aa[4];
#pragma unroll
            for (int k = 0; k < 4; ++k) {
                u32 i = i0 + k;
                aa[k] = (i < (u32)NB) ? cur[i] : 0u;
            }
            u32 sum = aa[0] + aa[1] + aa[2] + aa[3];
            u32 p = sum;
#pragma unroll
            for (int d = 1; d < 64; d <<= 1) {
                u32 x = (u32)__shfl_up((int)p, d, 64);
                if (lane >= d) p += x;
            }
            u32 excl = p - sum;
            if (lane == 63) wS[w] = p;
            __syncthreads();
            u32 woff = 0;
            for (int k = 0; k < w; ++k) woff += wS[k];
            u32 o0 = woff + excl;
            u32 oo[4] = {o0, o0 + aa[0], o0 + aa[0] + aa[1],
                         o0 + aa[0] + aa[1] + aa[2]};
#pragma unroll
            for (int k = 0; k < 4; ++k) {
                u32 i = i0 + k;
                if (i < (u32)NB) {
                    offs[i] = oo[k];
                    segtab[b * (NB + 1) + i] = (u16)oo[k];
                    cur[i] = 0u;
                }
            }
            if (tid == 0) segtab[b * (NB + 1) + NB] = (u16)nrec;
        }
        __syncthreads();

        auto srcMask = [&](u32 src) -> u64 {
            u32 slot = (src * 2654435761u) >> 25;
            while (true) {
                u32 k = hsKey[slot];
                if (k == src) return 1ull << hsBit[slot];
                if (k == HEMPTY) return 0ull;
                slot = (slot + 1) & 127u;
            }
        };

        // pass 2: place records + depth-1 NFg push (edges from regs)
#pragma unroll
        for (int k = 0; k < 4; ++k) {
            int i = tid + k * NTH;
            if (i < ne) {
                u32 uu = eu[k], vv = ev[k];
                u32 b1 = vv >> BSH;
                cbuf[offs[b1] + atomicAdd(&cur[b1], 1u)] = (uu << BSH) | (vv & (BN - 1));
                u32 b2 = uu >> BSH;
                cbuf[offs[b2] + atomicAdd(&cur[b2], 1u)] = (vv << BSH) | (uu & (BN - 1));
                if (uu != vv) {   // self-loop guard keeps NFg == depth-1 exactly
                    u64 m1 = srcMask(uu);
                    if (m1) atomicOr(&NFg[vv], m1);
                    u64 m2 = srcMask(vv);
                    if (m2) atomicOr(&NFg[uu], m2);
                }
            }
        }
        for (int i = tid + 4 * NTH; i < ne; i += NTH) {  // safety tail
            u32 uu = (u32)h[lo + i], vv = (u32)t[lo + i];
            u32 b1 = vv >> BSH;
            cbuf[offs[b1] + atomicAdd(&cur[b1], 1u)] = (uu << BSH) | (vv & (BN - 1));
            u32 b2 = uu >> BSH;
            cbuf[offs[b2] + atomicAdd(&cur[b2], 1u)] = (vv << BSH) | (uu & (BN - 1));
            if (uu != vv) {
                u64 m1 = srcMask(uu);
                if (m1) atomicOr(&NFg[vv], m1);
                u64 m2 = srcMask(vv);
                if (m2) atomicOr(&NFg[uu], m2);
            }
        }
        __syncthreads();
        for (int i = tid; i < nrec; i += NTH) recs[b * CAPC + i] = cbuf[i];
    }
    gbar(bar, 2 * nb);

    // ---- phase 2: merge chunk-major -> LDS bucket records + depth 2 ----
    u32 T;
    {
        if (tid < BN) NF[tid] = 0ull;
        if (tid < 64) srcL[tid] = srcPack[tid];

        u32 c0 = (u32)tid * 4;
        u32 ll[4];
#pragma unroll
        for (int k = 0; k < 4; ++k) {
            u32 c = c0 + k;
            u32 l_ = 0u;
            if (c < (u32)NB) {
                u32 a = segtab[c * (NB + 1) + b];
                u32 e = segtab[c * (NB + 1) + b + 1];
                s0a[c] = (u16)a;
                l_ = e - a;
            }
            ll[k] = l_;
        }
        u32 sum = ll[0] + ll[1] + ll[2] + ll[3];
        u32 p = sum;
#pragma unroll
        for (int d = 1; d < 64; d <<= 1) {
            u32 x = (u32)__shfl_up((int)p, d, 64);
            if (lane >= d) p += x;
        }
        u32 excl = p - sum;
        if (lane == 63) wS2[w] = p;
        __syncthreads();
        u32 woff = 0;
        for (int k = 0; k < w; ++k) woff += wS2[k];
        u32 base = woff + excl;
        loff[c0]     = base;
        loff[c0 + 1] = base + ll[0];
        loff[c0 + 2] = base + ll[0] + ll[1];
        loff[c0 + 3] = base + ll[0] + ll[1] + ll[2];
        if (tid == NTH - 1) loff[MAXC] = base + sum;
        __syncthreads();
        T = min(loff[MAXC], (u32)CAPG);

        // per-thread contiguous range; one binsearch, then moving pointer
        u32 per = (T + NTH - 1) / NTH;
        u32 j0 = min((u32)tid * per, T), j1 = min(j0 + per, T);
        if (j0 < j1) {
            int c = 0;
#pragma unroll
            for (int step = 512; step >= 1; step >>= 1)
                if (c + step <= MAXC - 1 && loff[c + step] <= j0) c += step;
            for (u32 j = j0; j < j1; ++j) {
                while (loff[c + 1] <= j) ++c;
                buf2[j] = recs[(u32)c * CAPC + (u32)s0a[c] + (j - loff[c])];
            }
        }
        __syncthreads();

        // depth-2 gather from LDS records
        u32 r = tid;
        for (; r + 3u * NTH < T; r += 4u * NTH) {
            u32 r0 = buf2[r],           r1 = buf2[r + NTH];
            u32 r2 = buf2[r + 2 * NTH], r3 = buf2[r + 3 * NTH];
            u64 f0 = NFg[r0 >> BSH], f1 = NFg[r1 >> BSH];
            u64 f2 = NFg[r2 >> BSH], f3 = NFg[r3 >> BSH];
            if (f0) atomicOr(&NF[r0 & (BN - 1)], f0);
            if (f1) atomicOr(&NF[r1 & (BN - 1)], f1);
            if (f2) atomicOr(&NF[r2 & (BN - 1)], f2);
            if (f3) atomicOr(&NF[r3 & (BN - 1)], f3);
        }
        for (; r < T; r += NTH) {
            u32 r0 = buf2[r];
            u64 f0 = NFg[r0 >> BSH];
            if (f0) atomicOr(&NF[r0 & (BN - 1)], f0);
        }
        __syncthreads();
        if (tid < BN) {
            int n = b * BN + tid;
            u64 v2 = 0ull, cnt = 0ull;
            if (n < N) {
                u64 srcbit = 0ull;
                for (int k = 0; k < 64; ++k) {
                    u32 pk = srcL[k];
                    if (pk != HEMPTY && (int)(pk >> BSH) == n)
                        srcbit |= 1ull << (pk & (BN - 1));
                }
                u64 nf1 = NFg[n];
                u64 v1 = srcbit | nf1;
                u64 newly2 = NF[tid] & ~v1;
                v2 = v1 | newly2;
                F2g[n] = newly2;
                cnt = (srcbit ? 1ull : 0ull)
                    | ((u64)__popcll(nf1) << 8)
                    | ((u64)__popcll(newly2) << 16);
            }
            Vl[tid] = v2;
            CNTl[tid] = cnt;
        }
    }
    gbar(bar, 3 * nb);

    auto depth_pass = [&](const u64* __restrict__ Fin) {
        u32 r = tid;
        for (; r + 3u * NTH < T; r += 4u * NTH) {
            u32 r0 = buf2[r],           r1 = buf2[r + NTH];
            u32 r2 = buf2[r + 2 * NTH], r3 = buf2[r + 3 * NTH];
            u64 f0 = Fin[r0 >> BSH], f1 = Fin[r1 >> BSH];
            u64 f2 = Fin[r2 >> BSH], f3 = Fin[r3 >> BSH];
            if (f0) atomicOr(&NF[r0 & (BN - 1)], f0);
            if (f1) atomicOr(&NF[r1 & (BN - 1)], f1);
            if (f2) atomicOr(&NF[r2 & (BN - 1)], f2);
            if (f3) atomicOr(&NF[r3 & (BN - 1)], f3);
        }
        for (; r < T; r += NTH) {
            u32 r0 = buf2[r];
            u64 f0 = Fin[r0 >> BSH];
            if (f0) atomicOr(&NF[r0 & (BN - 1)], f0);
        }
    };

    // ---- phase 3: depth 3 ----
    {
        if (tid < BN) NF[tid] = 0ull;
        __syncthreads();
        depth_pass(F2g);
        __syncthreads();
        if (tid < BN) {
            int n = b * BN + tid;
            if (n < N) {
                u64 vis = Vl[tid];
                u64 newly = NF[tid] & ~vis;
                F3g[n] = newly;
                if (newly) {
                    Vl[tid] = vis | newly;
                    CNTl[tid] += (u64)__popcll(newly) << 24;
                }
            }
        }
    }
    gbar(bar, 4 * nb);

    // ---- phase 4: depth 4 + output matmul ----
    {
        if (tid < BN) NF[tid] = 0ull;
        __syncthreads();
        depth_pass(F3g);
        __syncthreads();
        int nl = tid >> 2, q = tid & 3;   // 64 nodes x 4 float4 quads (D=16)
        int n = b * BN + nl;
        if (n >= N) return;
        u64 vis = Vl[nl];
        int c4 = __popcll(NF[nl] & ~vis);
        u64 c = CNTl[nl];
        int nv = *nvalid;
        float inv = 1.0f / (float)(nv > 0 ? nv : 1);
        float cd[MAXD + 1];
        int total = c4;
#pragma unroll
        for (int d = 0; d < 4; ++d) {
            int x = (int)((c >> (8 * d)) & 0xffull);
            total += x;
            cd[d] = (float)x;
        }
        cd[4] = (float)c4;
        cd[5] = (float)(nv - total);  // depth-5 + unreached

        const float4* e4 = (const float4*)embed;  // [6][4] float4 rows
        float4 acc = {0.f, 0.f, 0.f, 0.f};
#pragma unroll
        for (int d = 0; d <= MAXD; ++d) {
            float4 e = e4[d * 4 + q];
            acc.x += cd[d] * e.x; acc.y += cd[d] * e.y;
            acc.z += cd[d] * e.z; acc.w += cd[d] * e.w;
        }
        acc.x *= inv; acc.y *= inv; acc.z *= inv; acc.w *= inv;
        ((float4*)(out + (size_t)n * 16))[q] = acc;
    }
}

extern "C" void kernel_launch(void* const* d_in, const int* in_sizes, int n_in,
                              void* d_out, int out_size, void* d_ws, size_t ws_size,
                              hipStream_t stream) {
    const int*   h      = (const int*)d_in[0];
    const int*   t      = (const int*)d_in[1];
    const int*   anchor = (const int*)d_in[2];
    const float* embed  = (const float*)d_in[4];
    float*       out    = (float*)d_out;

    int E = in_sizes[0];
    int A = in_sizes[2];               // 32 anchor triples -> 64 sources
    int D = in_sizes[4] / (MAXD + 1);  // 16
    int N = out_size / D;              // 50000
    int NB = (N + BN - 1) >> BSH;      // 782 buckets = chunks = grid
    int CE = (E + NB - 1) / NB;        // 1024 edges per chunk
    int CAPC = 2 * CE;                 // 2048 records per chunk (exact)
    (void)D;

    u64* NFg     = (u64*)d_ws;
    u64* F2      = NFg + N;
    u64* F3      = F2 + N;
    u32* srcPack = (u32*)(F3 + N);
    int* nvalid  = (int*)(srcPack + 64);
    u32* bar     = (u32*)(nvalid + 1);
    u32* recs    = (u32*)(srcPack + 72);           // 16B-aligned
    u16* segtab  = (u16*)(recs + (size_t)NB * CAPC);

    // barrier counter must start at 0 each launch (graph-replay safe)
    hipMemsetAsync(bar, 0, 4, stream);

    size_t shA = (size_t)(CAPC + 2 * NB + 260) * sizeof(u32);
    size_t shB = (size_t)CAPG * 4 + 3 * BN * 8
               + (size_t)MAXC * 2 + (size_t)(MAXC + 1 + 4 + 64) * 4;
    size_t shmem = (((shA > shB ? shA : shB) + 255) / 256) * 256;

    fused<<<NB, NTH, shmem, stream>>>(h, t, E, CE, CAPC, NB, recs, segtab,
                                      anchor, A, NFg, srcPack, nvalid, bar,
                                      F2, F3, embed, out, N);
}